// Round 4
// baseline (799.601 us; speedup 1.0000x reference)
//
#include <hip/hip_runtime.h>

#define N_EDGES 1048576
#define N_GRAPH 512
#define MAXE    3072

typedef __attribute__((ext_vector_type(4))) float floatx4;

// ---------------- workspace zero ----------------
__global__ void zero_kernel(unsigned* __restrict__ p, int n) {
    int i = blockIdx.x * blockDim.x + threadIdx.x;
    if (i < n) p[i] = 0u;
}

// ---------------- edge bucketing ----------------
__global__ void hist_kernel(const int* __restrict__ dst, unsigned* __restrict__ counts) {
    __shared__ unsigned h[512];
    for (int i = threadIdx.x; i < 512; i += 256) h[i] = 0;
    __syncthreads();
    int stride = gridDim.x * blockDim.x;
    for (int e = blockIdx.x * blockDim.x + threadIdx.x; e < N_EDGES; e += stride)
        atomicAdd(&h[((unsigned)dst[e]) >> 7], 1u);
    __syncthreads();
    for (int i = threadIdx.x; i < 512; i += 256)
        if (h[i]) atomicAdd(&counts[i], h[i]);
}

__global__ void scan_kernel(const unsigned* __restrict__ counts,
                            unsigned* __restrict__ base, unsigned* __restrict__ cursor) {
    __shared__ unsigned s[512];
    int t = threadIdx.x;
    unsigned my = counts[t];
    s[t] = my;
    __syncthreads();
    for (int d = 1; d < 512; d <<= 1) {
        unsigned v = (t >= d) ? s[t - d] : 0u;
        __syncthreads();
        s[t] += v;
        __syncthreads();
    }
    base[t + 1] = s[t];
    cursor[t]   = s[t] - my;
    if (t == 0) base[0] = 0;
}

__global__ void scatter_kernel(const int* __restrict__ src, const int* __restrict__ dst,
                               unsigned* __restrict__ cursor, unsigned short* __restrict__ ebuf) {
    int stride = gridDim.x * blockDim.x;
    for (int e = blockIdx.x * blockDim.x + threadIdx.x; e < N_EDGES; e += stride) {
        int sv = src[e], dv = dst[e];
        unsigned pos = atomicAdd(&cursor[((unsigned)dv) >> 7], 1u);
        ebuf[pos] = (unsigned short)((sv & 127) | ((dv & 127) << 8));
    }
}

// ---------------- fused per-graph GCN layer (VALU f32) ----------------
// grp = tid>>5 owns nodes grp*8..+7; cch = tid&31 = column in current 32-block.
// X from LDS (broadcast float4), W from global (L1/L2-hot, coalesced),
// f32 accumulate; then sym-normalized CSR aggregation + bias + tanh.
template<int CIN, int COUT>
__device__ void gcn_layer(const float* __restrict__ Xin, float* __restrict__ Xout,
                          const float* __restrict__ W, const float* __restrict__ Bv,
                          float* H, const float* dinv,
                          const int* offs, const unsigned char* csr, int tid)
{
    const int grp = tid >> 5, cch = tid & 31;

    for (int cb = 0; cb < COUT / 32; ++cb) {
        const int c = cb * 32 + cch;
        float a[8];
#pragma unroll
        for (int i = 0; i < 8; ++i) a[i] = 0.f;
        for (int k = 0; k < CIN; k += 4) {
            float w0 = W[(k + 0) * COUT + c];
            float w1 = W[(k + 1) * COUT + c];
            float w2 = W[(k + 2) * COUT + c];
            float w3 = W[(k + 3) * COUT + c];
#pragma unroll
            for (int ni = 0; ni < 8; ++ni) {
                floatx4 xv = *(const floatx4*)(Xin + (grp * 8 + ni) * CIN + k);
                a[ni] += xv[0] * w0;
                a[ni] += xv[1] * w1;
                a[ni] += xv[2] * w2;
                a[ni] += xv[3] * w3;
            }
        }
        __syncthreads();   // previous cb's aggregation finished reading H
#pragma unroll
        for (int ni = 0; ni < 8; ++ni)
            H[(grp * 8 + ni) * 32 + cch] = a[ni];
        __syncthreads();

        float bias = Bv[c];
        for (int ni = 0; ni < 8; ++ni) {
            int n = grp * 8 + ni;
            float dn = dinv[n];
            float acc = 0.f;
            int o0 = offs[n], o1 = offs[n + 1];
            for (int p = o0; p < o1; ++p) {
                int s = csr[p] & 127;
                acc += H[s * 32 + cch] * (dinv[s] * dn);
            }
            acc += H[n * 32 + cch] * (dn * dn);
            acc += bias;
            float v = tanhf(acc);
            v = fminf(fmaxf(v, -1.0f), 1.0f);
            Xout[n * COUT + c] = v;
        }
    }
    __syncthreads();
}

// ---------------- fused per-graph kernel ----------------
__global__ __launch_bounds__(512, 1) void mega_kernel(
    const float* __restrict__ x,
    const float* __restrict__ W1, const float* __restrict__ b1,
    const float* __restrict__ W2, const float* __restrict__ b2,
    const float* __restrict__ W3, const float* __restrict__ b3,
    const float* __restrict__ W4, const float* __restrict__ b4,
    const float* __restrict__ W5, const float* __restrict__ b5,
    const float* __restrict__ W6, const float* __restrict__ b6,
    const float* __restrict__ Wf1, const float* __restrict__ bf1,
    const float* __restrict__ Wf2, const float* __restrict__ bf2,
    const unsigned* __restrict__ base, const unsigned short* __restrict__ ebuf,
    float* __restrict__ out)
{
    __shared__ __align__(16) char pool[160912];
    float* X1   = (float*)(pool + 0);        // 128x128 f32 (layer-1 out)
    float* Xst  = (float*)(pool + 65536);    // 128x128 f32 (layer-1 in; dies after L1)
    float* X2   = (float*)(pool + 65536);    // 128x64  f32 (layer-2 out, overlays Xst)
    float* X3   = (float*)(pool + 98304);    // 128x32  f32
    float* X4   = (float*)(pool + 114688);   // 128x32  f32
    float* H    = (float*)(pool + 131072);   // 128x32 f32; later W5 (16KB) / W6 (10KB) stage
    float* SCR  = (float*)(pool + 147456);   // 8 KB phased tail scratch
    int*   ldeg = (int*)(pool + 155648);
    int*   offs = (int*)(pool + 156160);     // int[129]
    float* dinv = (float*)(pool + 156680);
    float* key  = (float*)(pool + 157192);
    unsigned short* ord = (unsigned short*)(pool + 157704);
    unsigned char*  csr = (unsigned char*)(pool + 157832);  // u8[3072]
    // tail phases in SCR:
    float* Zs   = SCR;                 // 16x64  (4096 B)
    float* ZMP  = SCR + 1024;          // 16x32  (2048 B)
    float* Z896 = SCR;                 // 896    (3584 B)  — after Zs dead
    float* PART = SCR + 1024;          // 4x128  (2048 B)  — after ZMP dead
    float* FC1  = SCR + 896;           // 128    (512  B)
    float* LG   = SCR + 1536;          // 17     (68   B)
    float* W5s  = H;                   // 16x256 f32 (16384 B exactly)
    float* W6s  = H;                   // 32x16x5 f32 (10240 B), after W5 dead

    const int g   = blockIdx.x;
    const int tid = threadIdx.x;
    const unsigned base_g = base[g];
    int cnt = (int)(base[g + 1] - base_g);
    if (cnt < 0)    cnt = 0;
    if (cnt > MAXE) cnt = MAXE;

    // ---- build local CSR (by dst) ----
    if (tid < 128) ldeg[tid] = 0;
    __syncthreads();
    for (int e = tid; e < cnt; e += 512) {
        unsigned v = ebuf[base_g + e];
        atomicAdd(&ldeg[(v >> 8) & 127], 1);
    }
    __syncthreads();
    if (tid < 128) offs[tid + 1] = ldeg[tid];
    if (tid == 0)  offs[0] = 0;
    __syncthreads();
    for (int d = 1; d < 128; d <<= 1) {
        int v = 0;
        if (tid < 128 && tid >= d) v = offs[tid + 1 - d];
        __syncthreads();
        if (tid < 128 && tid >= d) offs[tid + 1] += v;
        __syncthreads();
    }
    if (tid < 128) {
        dinv[tid] = 1.0f / sqrtf((float)(1 + ldeg[tid]));   // self-loop + in-degree
        ldeg[tid] = offs[tid];                               // repurpose as cursor
    }
    __syncthreads();
    for (int e = tid; e < cnt; e += 512) {
        unsigned v = ebuf[base_g + e];
        int dn_ = (v >> 8) & 127, sn = v & 127;
        int p = atomicAdd(&ldeg[dn_], 1);
        csr[p] = (unsigned char)sn;
    }
    // ---- stage x tile (f32, vectorized) ----
    const float* xg = x + (size_t)g * 128 * 128;
    for (int idx = tid; idx < 4096; idx += 512)
        *(uint4*)((char*)Xst + idx * 16) = *(const uint4*)((const char*)xg + idx * 16);
    __syncthreads();

    // ---- 4 GCN layers ----
    gcn_layer<128, 128>(Xst, X1, W1, b1, H, dinv, offs, csr, tid);
    gcn_layer<128,  64>(X1,  X2, W2, b2, H, dinv, offs, csr, tid);
    gcn_layer< 64,  32>(X2,  X3, W3, b3, H, dinv, offs, csr, tid);
    gcn_layer< 32,  32>(X3,  X4, W4, b4, H, dinv, offs, csr, tid);

    // ---- sort key + stage W5 (f32 into H region) ----
    if (tid < 128) key[tid] = X4[tid * 32 + 31];
    if (tid < 64)  ord[tid] = (unsigned short)tid;    // safety default
    for (int idx = tid; idx < 4096; idx += 512) W5s[idx] = W5[idx];
    __syncthreads();
    // stable descending rank (= jnp.argsort(-key) first 64)
    if (tid < 128) {
        float myk = key[tid];
        int r = 0;
        for (int j = 0; j < 128; ++j) {
            float kj = key[j];
            r += (kj > myk) || (kj == myk && j < tid);
        }
        if (r < 64) ord[r] = (unsigned short)tid;
    }
    __syncthreads();

    // ---- z = relu(Conv1d(1,16,256,256)) on pooled rows ----
    {
        int q = tid >> 6, t = tid & 63;
        int node = ord[t] & 127;
        float z0 = b5[q];
        float z1 = b5[q + 8];
        const float* w5a = W5s + q * 256;
        const float* w5b = W5s + (q + 8) * 256;
        for (int jj = 0; jj < 128; ++jj) {          // lane-rotated: spread banks
            int j = (jj + t) & 127;
            float pv = X1[node * 128 + j];
            z0 += pv * w5a[j]; z1 += pv * w5b[j];
        }
        for (int jj = 0; jj < 64; ++jj) {
            int j = (jj + t) & 63;
            float pv = X2[node * 64 + j];
            z0 += pv * w5a[128 + j]; z1 += pv * w5b[128 + j];
        }
        for (int jj = 0; jj < 32; ++jj) {
            int j = (jj + t) & 31;
            float pv = X3[node * 32 + j];
            z0 += pv * w5a[192 + j]; z1 += pv * w5b[192 + j];
        }
        for (int jj = 0; jj < 32; ++jj) {
            int j = (jj + t) & 31;
            float pv = X4[node * 32 + j];
            z0 += pv * w5a[224 + j]; z1 += pv * w5b[224 + j];
        }
        Zs[q * 64 + t]       = fmaxf(z0, 0.f);
        Zs[(q + 8) * 64 + t] = fmaxf(z1, 0.f);
    }
    __syncthreads();
    // ---- maxpool(2,2) ----
    {
        int c = tid >> 5, p = tid & 31;
        ZMP[c * 32 + p] = fmaxf(Zs[c * 64 + 2 * p], Zs[c * 64 + 2 * p + 1]);
    }
    __syncthreads();
    // ---- stage W6 (over dead W5) ----
    for (int idx = tid; idx < 2560; idx += 512) W6s[idx] = W6[idx];
    __syncthreads();
    // ---- conv1d(16,32,5) VALID + relu ----
    for (int oi = tid; oi < 896; oi += 512) {
        int oc = oi / 28, p = oi % 28;
        float s = b6[oc];
#pragma unroll
        for (int i = 0; i < 16; ++i) {
            const float* wrow = W6s + (oc * 16 + i) * 5;
#pragma unroll
            for (int k = 0; k < 5; ++k)
                s += ZMP[i * 32 + p + k] * wrow[k];
        }
        Z896[oi] = fmaxf(s, 0.f);      // Z896 overlays Zs (dead)
    }
    __syncthreads();
    // ---- fc1 (896->128), split-K x4 ----
    {
        int f = tid & 127, q = tid >> 7;
        float s = 0.f;
        for (int i = q * 224; i < (q + 1) * 224; ++i)
            s += Z896[i] * Wf1[i * 128 + f];
        PART[q * 128 + f] = s;         // PART overlays ZMP (dead)
    }
    __syncthreads();
    if (tid < 128) {
        float s = PART[tid] + PART[128 + tid] + PART[256 + tid] + PART[384 + tid]
                + bf1[tid];
        FC1[tid] = fmaxf(s, 0.f);
    }
    __syncthreads();
    // ---- fc2 (128->10) + log_softmax ----
    if (tid < 10) {
        float s = bf2[tid];
        for (int i = 0; i < 128; ++i) s += FC1[i] * Wf2[i * 10 + tid];
        LG[tid] = s;
    }
    __syncthreads();
    if (tid == 0) {
        float mx = LG[0];
        for (int i = 1; i < 10; ++i) mx = fmaxf(mx, LG[i]);
        float se = 0.f;
        for (int i = 0; i < 10; ++i) se += expf(LG[i] - mx);
        LG[16] = mx + logf(se);
    }
    __syncthreads();
    if (tid < 10)
        out[g * 10 + tid] = LG[tid] - LG[16];
}

extern "C" void kernel_launch(void* const* d_in, const int* in_sizes, int n_in,
                              void* d_out, int out_size, void* d_ws, size_t ws_size,
                              hipStream_t stream) {
    (void)in_sizes; (void)n_in; (void)out_size; (void)ws_size;
    const float* x   = (const float*)d_in[0];
    const float* W1  = (const float*)d_in[1];
    const float* b1  = (const float*)d_in[2];
    const float* W2  = (const float*)d_in[3];
    const float* b2  = (const float*)d_in[4];
    const float* W3  = (const float*)d_in[5];
    const float* b3  = (const float*)d_in[6];
    const float* W4  = (const float*)d_in[7];
    const float* b4  = (const float*)d_in[8];
    const float* W5  = (const float*)d_in[9];
    const float* b5  = (const float*)d_in[10];
    const float* W6  = (const float*)d_in[11];
    const float* b6  = (const float*)d_in[12];
    const float* Wf1 = (const float*)d_in[13];
    const float* bf1 = (const float*)d_in[14];
    const float* Wf2 = (const float*)d_in[15];
    const float* bf2 = (const float*)d_in[16];
    const int* ei  = (const int*)d_in[17];
    const int* src = ei;
    const int* dst = ei + N_EDGES;

    char* ws = (char*)d_ws;
    unsigned* counts      = (unsigned*)(ws);
    unsigned* base        = (unsigned*)(ws + 2048);       // u32[513]
    unsigned* cursor      = (unsigned*)(ws + 4160);       // u32[512]
    unsigned short* ebuf  = (unsigned short*)(ws + 6400); // u16[E]

    zero_kernel<<<1, 512, 0, stream>>>(counts, 512);
    hist_kernel<<<256, 256, 0, stream>>>(dst, counts);
    scan_kernel<<<1, 512, 0, stream>>>(counts, base, cursor);
    scatter_kernel<<<512, 256, 0, stream>>>(src, dst, cursor, ebuf);
    mega_kernel<<<N_GRAPH, 512, 0, stream>>>(x, W1, b1, W2, b2, W3, b3, W4, b4,
                                             W5, b5, W6, b6, Wf1, bf1, Wf2, bf2,
                                             base, ebuf, (float*)d_out);
}

// Round 5
// 421.155 us; speedup vs baseline: 1.8986x; 1.8986x over previous
//
#include <hip/hip_runtime.h>

#define N_EDGES 1048576
#define N_GRAPH 512
#define MAXE    3072
#define CPAD    64          // counter padding stride (u32) = 256 B = 1 L2 channel slot

typedef __attribute__((ext_vector_type(4))) float floatx4;

// ---------------- workspace zero ----------------
__global__ void zero_kernel(unsigned* __restrict__ p, int n) {
    int i = blockIdx.x * blockDim.x + threadIdx.x;
    if (i < n) p[i] = 0u;
}

// ---------------- edge bucketing ----------------
__global__ void hist_kernel(const int* __restrict__ dst, unsigned* __restrict__ counts) {
    __shared__ unsigned h[512];
    for (int i = threadIdx.x; i < 512; i += 256) h[i] = 0;
    __syncthreads();
    int stride = gridDim.x * blockDim.x;
    for (int e = blockIdx.x * blockDim.x + threadIdx.x; e < N_EDGES; e += stride)
        atomicAdd(&h[((unsigned)dst[e]) >> 7], 1u);
    __syncthreads();
    for (int i = threadIdx.x; i < 512; i += 256)
        if (h[i]) atomicAdd(&counts[i * CPAD], h[i]);
}

__global__ void scan_kernel(const unsigned* __restrict__ counts,
                            unsigned* __restrict__ base, unsigned* __restrict__ cursor) {
    __shared__ unsigned s[512];
    int t = threadIdx.x;
    unsigned my = counts[t * CPAD];
    s[t] = my;
    __syncthreads();
    for (int d = 1; d < 512; d <<= 1) {
        unsigned v = (t >= d) ? s[t - d] : 0u;
        __syncthreads();
        s[t] += v;
        __syncthreads();
    }
    base[t + 1] = s[t];
    cursor[t * CPAD] = s[t] - my;
    if (t == 0) base[0] = 0;
}

__global__ void scatter_kernel(const int* __restrict__ src, const int* __restrict__ dst,
                               unsigned* __restrict__ cursor, unsigned short* __restrict__ ebuf) {
    int stride = gridDim.x * blockDim.x;
    for (int e = blockIdx.x * blockDim.x + threadIdx.x; e < N_EDGES; e += stride) {
        int sv = src[e], dv = dst[e];
        unsigned pos = atomicAdd(&cursor[(((unsigned)dv) >> 7) * CPAD], 1u);
        ebuf[pos] = (unsigned short)((sv & 127) | ((dv & 127) << 8));
    }
}

// ---------------- fused per-graph GCN layer (VALU f32, 1024 thr) ----------------
// grp = tid>>5 (32 groups) owns nodes grp*4..+3; cch = tid&31 = column in block.
template<int CIN, int COUT>
__device__ void gcn_layer(const float* __restrict__ Xin, float* __restrict__ Xout,
                          const float* __restrict__ W, const float* __restrict__ Bv,
                          float* H, const float* dinv,
                          const int* offs, const unsigned char* csr, int tid)
{
    const int grp = tid >> 5, cch = tid & 31;

    for (int cb = 0; cb < COUT / 32; ++cb) {
        const int c = cb * 32 + cch;
        float a[4];
#pragma unroll
        for (int i = 0; i < 4; ++i) a[i] = 0.f;
        for (int k = 0; k < CIN; k += 4) {
            float w0 = W[(k + 0) * COUT + c];
            float w1 = W[(k + 1) * COUT + c];
            float w2 = W[(k + 2) * COUT + c];
            float w3 = W[(k + 3) * COUT + c];
#pragma unroll
            for (int ni = 0; ni < 4; ++ni) {
                floatx4 xv = *(const floatx4*)(Xin + (grp * 4 + ni) * CIN + k);
                a[ni] += xv[0] * w0;
                a[ni] += xv[1] * w1;
                a[ni] += xv[2] * w2;
                a[ni] += xv[3] * w3;
            }
        }
        __syncthreads();   // previous cb's aggregation finished reading H
#pragma unroll
        for (int ni = 0; ni < 4; ++ni)
            H[(grp * 4 + ni) * 32 + cch] = a[ni];
        __syncthreads();

        float bias = Bv[c];
        for (int ni = 0; ni < 4; ++ni) {
            int n = grp * 4 + ni;
            float dn = dinv[n];
            float acc = 0.f;
            int o0 = offs[n], o1 = offs[n + 1];
            for (int p = o0; p < o1; ++p) {
                int s = csr[p] & 127;
                acc += H[s * 32 + cch] * (dinv[s] * dn);
            }
            acc += H[n * 32 + cch] * (dn * dn);
            acc += bias;
            float v = tanhf(acc);
            v = fminf(fmaxf(v, -1.0f), 1.0f);
            Xout[n * COUT + c] = v;
        }
    }
    __syncthreads();
}

// ---------------- fused per-graph kernel ----------------
__global__ __launch_bounds__(1024, 1) void mega_kernel(
    const float* __restrict__ x,
    const float* __restrict__ W1, const float* __restrict__ b1,
    const float* __restrict__ W2, const float* __restrict__ b2,
    const float* __restrict__ W3, const float* __restrict__ b3,
    const float* __restrict__ W4, const float* __restrict__ b4,
    const float* __restrict__ W5, const float* __restrict__ b5,
    const float* __restrict__ W6, const float* __restrict__ b6,
    const float* __restrict__ Wf1, const float* __restrict__ bf1,
    const float* __restrict__ Wf2, const float* __restrict__ bf2,
    const unsigned* __restrict__ base, const unsigned short* __restrict__ ebuf,
    float* __restrict__ out)
{
    __shared__ __align__(16) char pool[160912];
    float* X1   = (float*)(pool + 0);        // 128x128 f32 (layer-1 out)
    float* Xst  = (float*)(pool + 65536);    // 128x128 f32 (layer-1 in; dies after L1)
    float* X2   = (float*)(pool + 65536);    // 128x64  f32 (layer-2 out, overlays Xst)
    float* X3   = (float*)(pool + 98304);    // 128x32  f32
    float* X4   = (float*)(pool + 114688);   // 128x32  f32
    float* H    = (float*)(pool + 131072);   // 128x32 f32; later W5/W6 stage
    float* SCR  = (float*)(pool + 147456);   // 8 KB phased tail scratch
    int*   ldeg = (int*)(pool + 155648);
    int*   offs = (int*)(pool + 156160);     // int[129]
    float* dinv = (float*)(pool + 156680);
    float* key  = (float*)(pool + 157192);
    unsigned short* ord = (unsigned short*)(pool + 157704);
    unsigned char*  csr = (unsigned char*)(pool + 157832);  // u8[3072]
    // tail phases in SCR (floats 0..2048 = 8 KB):
    float* Zs   = SCR;                 // 16x64 = 1024 f  (phase A)
    float* ZMP  = SCR + 1024;          // 16x32 = 512  f  (phase A/B)
    float* Z896 = SCR;                 // 896 f (phase B, overlays dead Zs)
    float* PART = SCR + 1024;          // 8x128 = 1024 f (phase C, overlays dead ZMP)
    float* FC1  = SCR + 896;           // 128 f
    float* LG   = SCR;                 // 17 f (phase D, overlays dead Z896)
    float* W5s  = H;                   // 16x256 f32 (16 KB exactly)
    float* W6s  = H;                   // 32x16x5 f32 (10 KB), after W5 dead

    const int g   = blockIdx.x;
    const int tid = threadIdx.x;
    const unsigned base_g = base[g];
    int cnt = (int)(base[g + 1] - base_g);
    if (cnt < 0)    cnt = 0;
    if (cnt > MAXE) cnt = MAXE;

    // ---- build local CSR (by dst) ----
    if (tid < 128) ldeg[tid] = 0;
    __syncthreads();
    for (int e = tid; e < cnt; e += 1024) {
        unsigned v = ebuf[base_g + e];
        atomicAdd(&ldeg[(v >> 8) & 127], 1);
    }
    __syncthreads();
    if (tid < 128) offs[tid + 1] = ldeg[tid];
    if (tid == 0)  offs[0] = 0;
    __syncthreads();
    for (int d = 1; d < 128; d <<= 1) {
        int v = 0;
        if (tid < 128 && tid >= d) v = offs[tid + 1 - d];
        __syncthreads();
        if (tid < 128 && tid >= d) offs[tid + 1] += v;
        __syncthreads();
    }
    if (tid < 128) {
        dinv[tid] = 1.0f / sqrtf((float)(1 + ldeg[tid]));   // self-loop + in-degree
        ldeg[tid] = offs[tid];                               // repurpose as cursor
    }
    __syncthreads();
    for (int e = tid; e < cnt; e += 1024) {
        unsigned v = ebuf[base_g + e];
        int dn_ = (v >> 8) & 127, sn = v & 127;
        int p = atomicAdd(&ldeg[dn_], 1);
        csr[p] = (unsigned char)sn;
    }
    // ---- stage x tile (f32, vectorized) ----
    const float* xg = x + (size_t)g * 128 * 128;
    for (int idx = tid; idx < 4096; idx += 1024)
        *(uint4*)((char*)Xst + idx * 16) = *(const uint4*)((const char*)xg + idx * 16);
    __syncthreads();

    // ---- 4 GCN layers ----
    gcn_layer<128, 128>(Xst, X1, W1, b1, H, dinv, offs, csr, tid);
    gcn_layer<128,  64>(X1,  X2, W2, b2, H, dinv, offs, csr, tid);
    gcn_layer< 64,  32>(X2,  X3, W3, b3, H, dinv, offs, csr, tid);
    gcn_layer< 32,  32>(X3,  X4, W4, b4, H, dinv, offs, csr, tid);

    // ---- sort key + stage W5 (f32 into H region) ----
    if (tid < 128) key[tid] = X4[tid * 32 + 31];
    if (tid < 64)  ord[tid] = (unsigned short)tid;    // safety default
    for (int idx = tid; idx < 4096; idx += 1024) W5s[idx] = W5[idx];
    __syncthreads();
    // stable descending rank (= jnp.argsort(-key) first 64)
    if (tid < 128) {
        float myk = key[tid];
        int r = 0;
        for (int j = 0; j < 128; ++j) {
            float kj = key[j];
            r += (kj > myk) || (kj == myk && j < tid);
        }
        if (r < 64) ord[r] = (unsigned short)tid;
    }
    __syncthreads();

    // ---- z = relu(Conv1d(1,16,256,256)) on pooled rows ----
    // 16 channel-groups x 64 nodes: lane computes one (channel, node) pair
    {
        int q = tid >> 6, t = tid & 63;          // q in [0,16), t in [0,64)
        int node = ord[t] & 127;
        float z0 = b5[q];
        const float* w5a = W5s + q * 256;
        for (int jj = 0; jj < 128; ++jj) {       // lane-rotated: spread banks
            int j = (jj + t) & 127;
            z0 += X1[node * 128 + j] * w5a[j];
        }
        for (int jj = 0; jj < 64; ++jj) {
            int j = (jj + t) & 63;
            z0 += X2[node * 64 + j] * w5a[128 + j];
        }
        for (int jj = 0; jj < 32; ++jj) {
            int j = (jj + t) & 31;
            z0 += X3[node * 32 + j] * w5a[192 + j];
        }
        for (int jj = 0; jj < 32; ++jj) {
            int j = (jj + t) & 31;
            z0 += X4[node * 32 + j] * w5a[224 + j];
        }
        Zs[q * 64 + t] = fmaxf(z0, 0.f);
    }
    __syncthreads();
    // ---- maxpool(2,2) ----
    if (tid < 512) {
        int c = tid >> 5, p = tid & 31;
        ZMP[c * 32 + p] = fmaxf(Zs[c * 64 + 2 * p], Zs[c * 64 + 2 * p + 1]);
    }
    __syncthreads();
    // ---- stage W6 (over dead W5) ----
    for (int idx = tid; idx < 2560; idx += 1024) W6s[idx] = W6[idx];
    __syncthreads();
    // ---- conv1d(16,32,5) VALID + relu ----
    if (tid < 896) {
        int oc = tid / 28, p = tid % 28;
        float s = b6[oc];
#pragma unroll
        for (int i = 0; i < 16; ++i) {
            const float* wrow = W6s + (oc * 16 + i) * 5;
#pragma unroll
            for (int k = 0; k < 5; ++k)
                s += ZMP[i * 32 + p + k] * wrow[k];
        }
        Z896[tid] = fmaxf(s, 0.f);               // overlays dead Zs
    }
    __syncthreads();
    // ---- fc1 (896->128), split-K x8 ----
    {
        int f = tid & 127, q = tid >> 7;         // q in [0,8)
        float s = 0.f;
        for (int i = q * 112; i < (q + 1) * 112; ++i)
            s += Z896[i] * Wf1[i * 128 + f];
        PART[q * 128 + f] = s;                   // overlays dead ZMP
    }
    __syncthreads();
    if (tid < 128) {
        float s = bf1[tid];
#pragma unroll
        for (int q = 0; q < 8; ++q) s += PART[q * 128 + tid];
        FC1[tid] = fmaxf(s, 0.f);
    }
    __syncthreads();
    // ---- fc2 (128->10) + log_softmax ----
    if (tid < 10) {
        float s = bf2[tid];
        for (int i = 0; i < 128; ++i) s += FC1[i] * Wf2[i * 10 + tid];
        LG[tid] = s;                              // overlays dead Z896 head
    }
    __syncthreads();
    if (tid == 0) {
        float mx = LG[0];
        for (int i = 1; i < 10; ++i) mx = fmaxf(mx, LG[i]);
        float se = 0.f;
        for (int i = 0; i < 10; ++i) se += expf(LG[i] - mx);
        LG[16] = mx + logf(se);
    }
    __syncthreads();
    if (tid < 10)
        out[g * 10 + tid] = LG[tid] - LG[16];
}

extern "C" void kernel_launch(void* const* d_in, const int* in_sizes, int n_in,
                              void* d_out, int out_size, void* d_ws, size_t ws_size,
                              hipStream_t stream) {
    (void)in_sizes; (void)n_in; (void)out_size; (void)ws_size;
    const float* x   = (const float*)d_in[0];
    const float* W1  = (const float*)d_in[1];
    const float* b1  = (const float*)d_in[2];
    const float* W2  = (const float*)d_in[3];
    const float* b2  = (const float*)d_in[4];
    const float* W3  = (const float*)d_in[5];
    const float* b3  = (const float*)d_in[6];
    const float* W4  = (const float*)d_in[7];
    const float* b4  = (const float*)d_in[8];
    const float* W5  = (const float*)d_in[9];
    const float* b5  = (const float*)d_in[10];
    const float* W6  = (const float*)d_in[11];
    const float* b6  = (const float*)d_in[12];
    const float* Wf1 = (const float*)d_in[13];
    const float* bf1 = (const float*)d_in[14];
    const float* Wf2 = (const float*)d_in[15];
    const float* bf2 = (const float*)d_in[16];
    const int* ei  = (const int*)d_in[17];
    const int* src = ei;
    const int* dst = ei + N_EDGES;

    char* ws = (char*)d_ws;
    unsigned* counts      = (unsigned*)(ws);                  // 512*CPAD u32 = 128 KB
    unsigned* base        = (unsigned*)(ws + 131072);         // u32[513]
    unsigned* cursor      = (unsigned*)(ws + 133632);         // 512*CPAD u32 = 128 KB
    unsigned short* ebuf  = (unsigned short*)(ws + 264704);   // u16[E] = 2 MB

    zero_kernel<<<64, 512, 0, stream>>>(counts, 512 * CPAD);
    hist_kernel<<<256, 256, 0, stream>>>(dst, counts);
    scan_kernel<<<1, 512, 0, stream>>>(counts, base, cursor);
    scatter_kernel<<<512, 256, 0, stream>>>(src, dst, cursor, ebuf);
    mega_kernel<<<N_GRAPH, 1024, 0, stream>>>(x, W1, b1, W2, b2, W3, b3, W4, b4,
                                              W5, b5, W6, b6, Wf1, bf1, Wf2, bf2,
                                              base, ebuf, (float*)d_out);
}